// Round 1
// baseline (768.164 us; speedup 1.0000x reference)
//
#include <hip/hip_runtime.h>

// CSAM: x:[32,64,192,192] f32, gamma:[1] f32
// energy[b,c,d] = <x[b,c,:], x[b,d,:]>  (N=36864)
// att = softmax(rowmax(energy) - energy)
// out = x + gamma * x * (att @ q)
//
// Phase 1+3 use bf16 MFMA 16x16x32 (A/B: [m=lane&15][k=quad*8+j], C/D: col=lane&15, row=quad*4+reg)

#define BATCH 32
#define CH 64
#define NSP 36864

// phase 1 (gram)
#define KSPLIT 36
#define KPER (NSP / KSPLIT)   // 1024
#define BK 128
#define SITER (KPER / BK)     // 8

// phase 3 (proj)
#define NB 128                // n-chunk per iteration
#define NCHUNK 8              // chunks per persistent block
#define NBLKY (NSP / (NB * NCHUNK))   // 36

using frag  = __attribute__((ext_vector_type(8))) short;   // 8 bf16 (4 VGPRs)
using f32x4 = __attribute__((ext_vector_type(4))) float;   // MFMA C/D

__device__ inline unsigned short f2bf(float f) {
    unsigned u = __builtin_bit_cast(unsigned, f);
    unsigned r = (u + 0x7FFFu + ((u >> 16) & 1u)) >> 16;   // RTNE
    return (unsigned short)r;
}
__device__ inline unsigned pack2(float a, float b) {
    return (unsigned)f2bf(a) | ((unsigned)f2bf(b) << 16);
}

// ---------------- Phase 1: Gram via MFMA, k-split, partial slices -----------
// part layout: [KSPLIT][BATCH][CH][CH] f32 (plain stores, no atomics/memset)
__global__ __launch_bounds__(256, 4) void gram_kernel(const float* __restrict__ x,
                                                      float* __restrict__ part) {
    const int b = blockIdx.x;
    const int kb = blockIdx.y;
    const int tid = threadIdx.x;
    const int wv = tid >> 6;
    const int lane = tid & 63;
    const int l15 = lane & 15;
    const int quad = lane >> 4;

    __shared__ unsigned short tile[CH][BK + 8];   // bf16, stride 272B (16B-mult, banks spread)

    const float* xb = x + (size_t)b * CH * NSP + (size_t)kb * KPER;

    f32x4 acc[4];
#pragma unroll
    for (int cb = 0; cb < 4; cb++)
#pragma unroll
        for (int r = 0; r < 4; r++) acc[cb][r] = 0.f;

    // prologue: issue loads for slab 0 (64 rows x 128 k fp32, coalesced float4)
    float4 v[8];
#pragma unroll
    for (int rep = 0; rep < 8; rep++) {
        int idx = rep * 256 + tid;        // 2048 float4 slots, 32/row
        int c = idx >> 5, kq = idx & 31;
        v[rep] = *(const float4*)&xb[(size_t)c * NSP + kq * 4];
    }

    for (int s = 0; s < SITER; s++) {
        __syncthreads();                  // prev iter's frag reads done
#pragma unroll
        for (int rep = 0; rep < 8; rep++) {
            int idx = rep * 256 + tid;
            int c = idx >> 5, kq = idx & 31;
            uint2 p;
            p.x = pack2(v[rep].x, v[rep].y);
            p.y = pack2(v[rep].z, v[rep].w);
            *(uint2*)&tile[c][kq * 4] = p;    // 8B aligned
        }
        __syncthreads();

        // prefetch next slab: HBM latency hides under this iter's MFMA
        if (s + 1 < SITER) {
#pragma unroll
            for (int rep = 0; rep < 8; rep++) {
                int idx = rep * 256 + tid;
                int c = idx >> 5, kq = idx & 31;
                v[rep] = *(const float4*)&xb[(size_t)c * NSP + (s + 1) * BK + kq * 4];
            }
        }

#pragma unroll
        for (int ks = 0; ks < 4; ks++) {      // four K=32 steps
            frag a = *(const frag*)&tile[wv * 16 + l15][ks * 32 + quad * 8];
#pragma unroll
            for (int cb = 0; cb < 4; cb++) {
                frag bb = *(const frag*)&tile[cb * 16 + l15][ks * 32 + quad * 8];
                acc[cb] = __builtin_amdgcn_mfma_f32_16x16x32_bf16(a, bb, acc[cb], 0, 0, 0);
            }
        }
    }

    float* eb = part + ((size_t)kb * BATCH + b) * CH * CH;
#pragma unroll
    for (int cb = 0; cb < 4; cb++)
#pragma unroll
        for (int r = 0; r < 4; r++) {
            int row = wv * 16 + quad * 4 + r;
            int col = cb * 16 + l15;
            eb[row * CH + col] = acc[cb][r];
        }
}

// ---------------- Phase 2: 36-way partial sum + inverted softmax -----------
__global__ __launch_bounds__(64) void softmax_kernel(const float* __restrict__ part,
                                                     float* __restrict__ att) {
    const int row = blockIdx.x;               // b*CH + c, 0..2047
    const int d = threadIdx.x;

    float e = 0.f;
#pragma unroll
    for (int kb = 0; kb < KSPLIT; kb++)
        e += part[(size_t)kb * (BATCH * CH * CH) + (size_t)row * CH + d];

    float m = e;
#pragma unroll
    for (int off = 32; off > 0; off >>= 1) m = fmaxf(m, __shfl_down(m, off));
    m = __shfl(m, 0);

    float en = m - e;

    float mx = en;
#pragma unroll
    for (int off = 32; off > 0; off >>= 1) mx = fmaxf(mx, __shfl_down(mx, off));
    mx = __shfl(mx, 0);

    float ex = __expf(en - mx);
    float s = ex;
#pragma unroll
    for (int off = 32; off > 0; off >>= 1) s += __shfl_down(s, off);
    s = __shfl(s, 0);

    att[(size_t)row * CH + d] = ex / s;
}

// ---------------- Phase 3: out = x + g*x*(att @ x), persistent blocks ------
__global__ __launch_bounds__(256, 3) void proj_kernel(const float* __restrict__ x,
                                                      const float* __restrict__ att,
                                                      const float* __restrict__ gamma,
                                                      float* __restrict__ out) {
    const int b = blockIdx.x;
    const int tid = threadIdx.x;
    const int wv = tid >> 6;
    const int lane = tid & 63;
    const int l15 = lane & 15;
    const int quad = lane >> 4;

    __shared__ float xs[CH][NB + 1];            // fp32 x tile, 33KB (stride 129: bank-spread)
    __shared__ unsigned short satt[CH][72];     // bf16 att, 9.2KB

    const float* xb = x + (size_t)b * CH * NSP;
    float* ob = out + (size_t)b * CH * NSP;

    // stage att[b] -> bf16 LDS (once per persistent block)
#pragma unroll
    for (int rep = 0; rep < 4; rep++) {
        int idx = rep * 256 + tid;              // 1024 float4 slots
        int c = idx >> 4, j = idx & 15;
        float4 a4 = *(const float4*)&att[(size_t)b * CH * CH + c * CH + j * 4];
        uint2 p;
        p.x = pack2(a4.x, a4.y);
        p.y = pack2(a4.z, a4.w);
        *(uint2*)&satt[c][j * 4] = p;
    }

    const float g = gamma[0];
    const int nbase = blockIdx.y * (NB * NCHUNK);

    // prologue: issue loads for chunk 0
    float4 v[8];
#pragma unroll
    for (int rep = 0; rep < 8; rep++) {
        int idx = rep * 256 + tid;              // 2048 float4 slots, 32/row
        int dd = idx >> 5, nq = idx & 31;
        v[rep] = *(const float4*)&xb[(size_t)dd * NSP + nbase + nq * 4];
    }

    for (int ch = 0; ch < NCHUNK; ch++) {
        const int n0 = nbase + ch * NB;

        __syncthreads();                        // prev chunk's xs readers done
#pragma unroll
        for (int rep = 0; rep < 8; rep++) {
            int idx = rep * 256 + tid;
            int dd = idx >> 5, nq = idx & 31;
            *(float4*)&xs[dd][nq * 4] = v[rep];
        }
        __syncthreads();                        // xs (and satt, first iter) visible

        // prefetch next chunk: latency hides under MFMA + epilogue
        if (ch + 1 < NCHUNK) {
#pragma unroll
            for (int rep = 0; rep < 8; rep++) {
                int idx = rep * 256 + tid;
                int dd = idx >> 5, nq = idx & 31;
                v[rep] = *(const float4*)&xb[(size_t)dd * NSP + n0 + NB + nq * 4];
            }
        }

        // wave wv owns spatial tiles {2wv, 2wv+1} (16 n each), all 4 channel-blocks
        f32x4 acc[2][4];
#pragma unroll
        for (int t = 0; t < 2; t++)
#pragma unroll
            for (int cb = 0; cb < 4; cb++)
#pragma unroll
                for (int r = 0; r < 4; r++) acc[t][cb][r] = 0.f;

#pragma unroll
        for (int ks = 0; ks < 2; ks++) {        // K=64 -> two K=32 steps
            frag af[4];
#pragma unroll
            for (int cb = 0; cb < 4; cb++)
                af[cb] = *(const frag*)&satt[cb * 16 + l15][ks * 32 + quad * 8];
#pragma unroll
            for (int t = 0; t < 2; t++) {
                int n = (wv * 2 + t) * 16 + l15;
                int k0 = ks * 32 + quad * 8;
                uint4 packed;
                packed.x = pack2(xs[k0 + 0][n], xs[k0 + 1][n]);
                packed.y = pack2(xs[k0 + 2][n], xs[k0 + 3][n]);
                packed.z = pack2(xs[k0 + 4][n], xs[k0 + 5][n]);
                packed.w = pack2(xs[k0 + 6][n], xs[k0 + 7][n]);
                frag bf = __builtin_bit_cast(frag, packed);
#pragma unroll
                for (int cb = 0; cb < 4; cb++)
                    acc[t][cb] = __builtin_amdgcn_mfma_f32_16x16x32_bf16(af[cb], bf, acc[t][cb], 0, 0, 0);
            }
        }

#pragma unroll
        for (int t = 0; t < 2; t++) {
            int n = (wv * 2 + t) * 16 + l15;
#pragma unroll
            for (int cb = 0; cb < 4; cb++)
#pragma unroll
                for (int r = 0; r < 4; r++) {
                    int c = cb * 16 + quad * 4 + r;
                    float xv = xs[c][n];
                    ob[(size_t)c * NSP + n0 + n] = fmaf(xv * g, acc[t][cb][r], xv);
                }
        }
    }
}

extern "C" void kernel_launch(void* const* d_in, const int* in_sizes, int n_in,
                              void* d_out, int out_size, void* d_ws, size_t ws_size,
                              hipStream_t stream) {
    const float* x = (const float*)d_in[0];
    const float* gamma = (const float*)d_in[1];
    float* out = (float*)d_out;

    float* part = (float*)d_ws;                               // 36*32*64*64 f32 = 18.9 MB
    float* att = part + (size_t)KSPLIT * BATCH * CH * CH;     // +512 KB

    gram_kernel<<<dim3(BATCH, KSPLIT), 256, 0, stream>>>(x, part);
    softmax_kernel<<<BATCH * CH, 64, 0, stream>>>(part, att);
    proj_kernel<<<dim3(BATCH, NBLKY), 256, 0, stream>>>(x, att, gamma, out);
}

// Round 2
// 687.107 us; speedup vs baseline: 1.1180x; 1.1180x over previous
//
#include <hip/hip_runtime.h>

// CSAM: x:[32,64,192,192] f32, gamma:[1] f32
// energy[b,c,d] = <x[b,c,:], x[b,d,:]>  (N=36864)
// att = softmax(rowmax(energy) - energy)
// out = x + gamma * x * (att @ q)
//
// Phase 1+3 use bf16 MFMA 16x16x32 (A/B: [m=lane&15][k=quad*8+j], C/D: col=lane&15, row=quad*4+reg)

#define BATCH 32
#define CH 64
#define NSP 36864

// phase 1 (gram): 32 k-slices -> 1024 blocks = exactly 4/CU resident
#define KSPLIT 32
#define KPER (NSP / KSPLIT)   // 1152
#define BK 128
#define SITER (KPER / BK)     // 9

// phase 3 (proj): 4 chunks/block -> 2304 blocks = exactly 9/CU (3 resident waves)
#define NB 128
#define NCHUNK 4
#define NBLKY (NSP / (NB * NCHUNK))   // 72
#define XSTR 132              // fp32 row stride: 16B-aligned rows (33*16B)

using frag  = __attribute__((ext_vector_type(8))) short;   // 8 bf16 (4 VGPRs)
using f32x4 = __attribute__((ext_vector_type(4))) float;   // MFMA C/D

__device__ inline unsigned short f2bf(float f) {
    unsigned u = __builtin_bit_cast(unsigned, f);
    unsigned r = (u + 0x7FFFu + ((u >> 16) & 1u)) >> 16;   // RTNE
    return (unsigned short)r;
}
__device__ inline unsigned pack2(float a, float b) {
    return (unsigned)f2bf(a) | ((unsigned)f2bf(b) << 16);
}
// per-row 16-col rotation: breaks bank alignment across 8-row groups,
// 16-granular so float4 spans survive
__device__ inline int rotn(int c, int n) {
    return (n + (((c >> 3) & 3) << 4)) & (NB - 1);
}

// ---------------- Phase 1: Gram via MFMA, k-split, partial slices -----------
// part layout: [KSPLIT][BATCH][CH][CH] f32 (plain stores, no atomics/memset)
__global__ __launch_bounds__(256, 4) void gram_kernel(const float* __restrict__ x,
                                                      float* __restrict__ part) {
    const int b = blockIdx.x;
    const int kb = blockIdx.y;
    const int tid = threadIdx.x;
    const int wv = tid >> 6;
    const int lane = tid & 63;
    const int l15 = lane & 15;
    const int quad = lane >> 4;

    // double-buffered bf16 tile -> single barrier per K-slab
    __shared__ unsigned short tile[2][CH][BK + 8];   // 2*64*136*2B = 34.8 KB

    const float* xb = x + (size_t)b * CH * NSP + (size_t)kb * KPER;

    f32x4 acc[4];
#pragma unroll
    for (int cb = 0; cb < 4; cb++)
#pragma unroll
        for (int r = 0; r < 4; r++) acc[cb][r] = 0.f;

    // prologue: issue loads for slab 0 (64 rows x 128 k fp32, coalesced float4)
    float4 v[8];
#pragma unroll
    for (int rep = 0; rep < 8; rep++) {
        int idx = rep * 256 + tid;        // 2048 float4 slots, 32/row
        int c = idx >> 5, kq = idx & 31;
        v[rep] = *(const float4*)&xb[(size_t)c * NSP + kq * 4];
    }

    int p = 0;
    for (int s = 0; s < SITER; s++) {
        // write staged regs -> tile[p]
#pragma unroll
        for (int rep = 0; rep < 8; rep++) {
            int idx = rep * 256 + tid;
            int c = idx >> 5, kq = idx & 31;
            uint2 pp;
            pp.x = pack2(v[rep].x, v[rep].y);
            pp.y = pack2(v[rep].z, v[rep].w);
            *(uint2*)&tile[p][c][kq * 4] = pp;    // 8B aligned
        }
        __syncthreads();
        // prefetch next slab: HBM latency hides under this slab's MFMA
        if (s + 1 < SITER) {
#pragma unroll
            for (int rep = 0; rep < 8; rep++) {
                int idx = rep * 256 + tid;
                int c = idx >> 5, kq = idx & 31;
                v[rep] = *(const float4*)&xb[(size_t)c * NSP + (s + 1) * BK + kq * 4];
            }
        }
#pragma unroll
        for (int ks = 0; ks < 4; ks++) {      // four K=32 steps
            frag a = *(const frag*)&tile[p][wv * 16 + l15][ks * 32 + quad * 8];
#pragma unroll
            for (int cb = 0; cb < 4; cb++) {
                frag bb = *(const frag*)&tile[p][cb * 16 + l15][ks * 32 + quad * 8];
                acc[cb] = __builtin_amdgcn_mfma_f32_16x16x32_bf16(a, bb, acc[cb], 0, 0, 0);
            }
        }
        p ^= 1;
    }

    float* eb = part + ((size_t)kb * BATCH + b) * CH * CH;
#pragma unroll
    for (int cb = 0; cb < 4; cb++)
#pragma unroll
        for (int r = 0; r < 4; r++) {
            int row = wv * 16 + quad * 4 + r;
            int col = cb * 16 + l15;
            eb[row * CH + col] = acc[cb][r];
        }
}

// ---------------- Phase 2: 32-way partial sum + inverted softmax -----------
__global__ __launch_bounds__(64) void softmax_kernel(const float* __restrict__ part,
                                                     float* __restrict__ att) {
    const int row = blockIdx.x;               // b*CH + c, 0..2047
    const int d = threadIdx.x;

    float e = 0.f;
#pragma unroll
    for (int kb = 0; kb < KSPLIT; kb++)
        e += part[(size_t)kb * (BATCH * CH * CH) + (size_t)row * CH + d];

    float m = e;
#pragma unroll
    for (int off = 32; off > 0; off >>= 1) m = fmaxf(m, __shfl_down(m, off));
    m = __shfl(m, 0);

    float en = m - e;

    float mx = en;
#pragma unroll
    for (int off = 32; off > 0; off >>= 1) mx = fmaxf(mx, __shfl_down(mx, off));
    mx = __shfl(mx, 0);

    float ex = __expf(en - mx);
    float s = ex;
#pragma unroll
    for (int off = 32; off > 0; off >>= 1) s += __shfl_down(s, off);
    s = __shfl(s, 0);

    att[(size_t)row * CH + d] = ex / s;
}

// ---------------- Phase 3: out = x + g*x*(att @ x) -------------------------
__global__ __launch_bounds__(256, 3) void proj_kernel(const float* __restrict__ x,
                                                      const float* __restrict__ att,
                                                      const float* __restrict__ gamma,
                                                      float* __restrict__ out) {
    const int b = blockIdx.x;
    const int tid = threadIdx.x;
    const int wv = tid >> 6;
    const int lane = tid & 63;
    const int l15 = lane & 15;
    const int quad = lane >> 4;

    __shared__ float xs[CH][XSTR];              // 33.8 KB, rotated columns
    __shared__ unsigned short satt[CH][72];     // bf16 att, 9.2 KB

    const float* xb = x + (size_t)b * CH * NSP;
    float* ob = out + (size_t)b * CH * NSP;

    // stage att[b] -> bf16 LDS (once per block; visible after first barrier)
#pragma unroll
    for (int rep = 0; rep < 4; rep++) {
        int idx = rep * 256 + tid;              // 1024 float4 slots
        int c = idx >> 4, j = idx & 15;
        float4 a4 = *(const float4*)&att[(size_t)b * CH * CH + c * CH + j * 4];
        uint2 pp;
        pp.x = pack2(a4.x, a4.y);
        pp.y = pack2(a4.z, a4.w);
        *(uint2*)&satt[c][j * 4] = pp;
    }

    const float g = gamma[0];
    const int nbase = blockIdx.y * (NB * NCHUNK);

    // prologue: issue loads for chunk 0
    float4 v[8];
#pragma unroll
    for (int rep = 0; rep < 8; rep++) {
        int idx = rep * 256 + tid;              // 2048 float4 slots, 32/row
        int dd = idx >> 5, nq = idx & 31;
        v[rep] = *(const float4*)&xb[(size_t)dd * NSP + nbase + nq * 4];
    }

    for (int ch = 0; ch < NCHUNK; ch++) {
        const int n0 = nbase + ch * NB;

        __syncthreads();                        // prev chunk's store-phase reads done
#pragma unroll
        for (int rep = 0; rep < 8; rep++) {
            int idx = rep * 256 + tid;
            int dd = idx >> 5, nq = idx & 31;
            *(float4*)&xs[dd][rotn(dd, nq * 4)] = v[rep];
        }
        __syncthreads();                        // xs (and satt, first iter) visible

        // prefetch next chunk: latency hides under MFMA + epilogue + store
        if (ch + 1 < NCHUNK) {
#pragma unroll
            for (int rep = 0; rep < 8; rep++) {
                int idx = rep * 256 + tid;
                int dd = idx >> 5, nq = idx & 31;
                v[rep] = *(const float4*)&xb[(size_t)dd * NSP + n0 + NB + nq * 4];
            }
        }

        // wave wv owns spatial tiles {2wv, 2wv+1} (16 n each), all 4 channel-blocks
        f32x4 acc[2][4];
#pragma unroll
        for (int t = 0; t < 2; t++)
#pragma unroll
            for (int cb = 0; cb < 4; cb++)
#pragma unroll
                for (int r = 0; r < 4; r++) acc[t][cb][r] = 0.f;

#pragma unroll
        for (int ks = 0; ks < 2; ks++) {        // K=64 -> two K=32 steps
            frag af[4];
#pragma unroll
            for (int cb = 0; cb < 4; cb++)
                af[cb] = *(const frag*)&satt[cb * 16 + l15][ks * 32 + quad * 8];
#pragma unroll
            for (int t = 0; t < 2; t++) {
                int n = (wv * 2 + t) * 16 + l15;
                int k0 = ks * 32 + quad * 8;
                // rot index for rows k0..k0+7: ((k0+j)>>3)&3 == quad for all j<8
                int np = (n + (quad << 4)) & (NB - 1);
                uint4 packed;
                packed.x = pack2(xs[k0 + 0][np], xs[k0 + 1][np]);
                packed.y = pack2(xs[k0 + 2][np], xs[k0 + 3][np]);
                packed.z = pack2(xs[k0 + 4][np], xs[k0 + 5][np]);
                packed.w = pack2(xs[k0 + 6][np], xs[k0 + 7][np]);
                frag bf = __builtin_bit_cast(frag, packed);
#pragma unroll
                for (int cb = 0; cb < 4; cb++)
                    acc[t][cb] = __builtin_amdgcn_mfma_f32_16x16x32_bf16(af[cb], bf, acc[t][cb], 0, 0, 0);
            }
        }

        // epilogue: result in place into xs (each wave owns disjoint n-stripe;
        // reads of block cb+1 never touch rows written by blocks <= cb)
#pragma unroll
        for (int t = 0; t < 2; t++) {
            int n = (wv * 2 + t) * 16 + l15;
#pragma unroll
            for (int cb = 0; cb < 4; cb++)
#pragma unroll
                for (int r = 0; r < 4; r++) {
                    int c = cb * 16 + quad * 4 + r;
                    int np = rotn(c, n);
                    float xv = xs[c][np];
                    xs[c][np] = fmaf(xv * g, acc[t][cb][r], xv);
                }
        }
        __syncthreads();                        // results visible

        // coalesced store: full rows, 1024B per wave-instruction (no partial lines)
#pragma unroll
        for (int rep = 0; rep < 8; rep++) {
            int idx = rep * 256 + tid;          // 2048 float4 slots, 32/row
            int dd = idx >> 5, nq = idx & 31;
            float4 r4 = *(const float4*)&xs[dd][rotn(dd, nq * 4)];
            *(float4*)&ob[(size_t)dd * NSP + n0 + nq * 4] = r4;
        }
    }
}

extern "C" void kernel_launch(void* const* d_in, const int* in_sizes, int n_in,
                              void* d_out, int out_size, void* d_ws, size_t ws_size,
                              hipStream_t stream) {
    const float* x = (const float*)d_in[0];
    const float* gamma = (const float*)d_in[1];
    float* out = (float*)d_out;

    float* part = (float*)d_ws;                               // 32*32*64*64 f32 = 16 MB
    float* att = part + (size_t)KSPLIT * BATCH * CH * CH;     // +512 KB

    gram_kernel<<<dim3(BATCH, KSPLIT), 256, 0, stream>>>(x, part);
    softmax_kernel<<<BATCH * CH, 64, 0, stream>>>(part, att);
    proj_kernel<<<dim3(BATCH, NBLKY), 256, 0, stream>>>(x, att, gamma, out);
}

// Round 3
// 598.860 us; speedup vs baseline: 1.2827x; 1.1474x over previous
//
#include <hip/hip_runtime.h>

// CSAM: x:[32,64,192,192] f32, gamma:[1] f32
// energy[b,c,d] = <x[b,c,:], x[b,d,:]>  (N=36864)
// att = softmax(rowmax(energy) - energy)
// out = x + gamma * x * (att @ q)
//
// Phase 1+3 use bf16 MFMA 16x16x32 (A/B: [m=lane&15][k=quad*8+j], C/D: col=lane&15, row=quad*4+reg)

#define BATCH 32
#define CH 64
#define NSP 36864

// phase 1 (gram): 48 k-slices -> 1536 blocks = exactly 6/CU resident
#define KSPLIT 48
#define KPER (NSP / KSPLIT)   // 768
#define BK 64
#define SITER (KPER / BK)     // 12

// phase 3 (proj): one-shot blocks, 9216 = 36/CU queued, 4 resident
#define NB 128
#define NBLKY (NSP / NB)      // 288
#define XSTR 132              // fp32 row stride: 16B-aligned rows (33*16B)

using frag  = __attribute__((ext_vector_type(8))) short;   // 8 bf16 (4 VGPRs)
using f32x4 = __attribute__((ext_vector_type(4))) float;   // MFMA C/D

__device__ inline unsigned short f2bf(float f) {
    unsigned u = __builtin_bit_cast(unsigned, f);
    unsigned r = (u + 0x7FFFu + ((u >> 16) & 1u)) >> 16;   // RTNE
    return (unsigned short)r;
}
__device__ inline unsigned pack2(float a, float b) {
    return (unsigned)f2bf(a) | ((unsigned)f2bf(b) << 16);
}
// per-row 16-col rotation: breaks bank alignment across 8-row groups,
// 16-granular so float4 spans survive
__device__ inline int rotn(int c, int n) {
    return (n + (((c >> 3) & 3) << 4)) & (NB - 1);
}

// ---------------- Phase 1: Gram via MFMA, k-split, partial slices -----------
// part layout: [KSPLIT][BATCH][CH][CH] f32 (plain stores, no atomics/memset)
__global__ __launch_bounds__(256, 6) void gram_kernel(const float* __restrict__ x,
                                                      float* __restrict__ part) {
    const int b = blockIdx.x;
    const int kb = blockIdx.y;
    const int tid = threadIdx.x;
    const int wv = tid >> 6;
    const int lane = tid & 63;
    const int l15 = lane & 15;
    const int quad = lane >> 4;

    // double-buffered bf16 tile, single barrier per K-slab; 18.4 KB -> 6 blocks/CU
    __shared__ unsigned short tile[2][CH][BK + 8];

    const float* xb = x + (size_t)b * CH * NSP + (size_t)kb * KPER;

    f32x4 acc[4];
#pragma unroll
    for (int cb = 0; cb < 4; cb++)
#pragma unroll
        for (int r = 0; r < 4; r++) acc[cb][r] = 0.f;

    // prologue: issue loads for slab 0 (64 rows x 64 k fp32, coalesced float4)
    float4 v[4];
#pragma unroll
    for (int rep = 0; rep < 4; rep++) {
        int idx = rep * 256 + tid;        // 1024 float4 slots, 16/row
        int c = idx >> 4, kq = idx & 15;
        v[rep] = *(const float4*)&xb[(size_t)c * NSP + kq * 4];
    }

    int p = 0;
    for (int s = 0; s < SITER; s++) {
        // write staged regs -> tile[p]
#pragma unroll
        for (int rep = 0; rep < 4; rep++) {
            int idx = rep * 256 + tid;
            int c = idx >> 4, kq = idx & 15;
            uint2 pp;
            pp.x = pack2(v[rep].x, v[rep].y);
            pp.y = pack2(v[rep].z, v[rep].w);
            *(uint2*)&tile[p][c][kq * 4] = pp;    // 8B aligned
        }
        __syncthreads();
        // prefetch next slab: HBM latency hides under this slab's MFMA + 5 peer blocks
        if (s + 1 < SITER) {
#pragma unroll
            for (int rep = 0; rep < 4; rep++) {
                int idx = rep * 256 + tid;
                int c = idx >> 4, kq = idx & 15;
                v[rep] = *(const float4*)&xb[(size_t)c * NSP + (s + 1) * BK + kq * 4];
            }
        }
#pragma unroll
        for (int ks = 0; ks < 2; ks++) {      // two K=32 steps
            frag a = *(const frag*)&tile[p][wv * 16 + l15][ks * 32 + quad * 8];
#pragma unroll
            for (int cb = 0; cb < 4; cb++) {
                frag bb = *(const frag*)&tile[p][cb * 16 + l15][ks * 32 + quad * 8];
                acc[cb] = __builtin_amdgcn_mfma_f32_16x16x32_bf16(a, bb, acc[cb], 0, 0, 0);
            }
        }
        p ^= 1;
    }

    float* eb = part + ((size_t)kb * BATCH + b) * CH * CH;
#pragma unroll
    for (int cb = 0; cb < 4; cb++)
#pragma unroll
        for (int r = 0; r < 4; r++) {
            int row = wv * 16 + quad * 4 + r;
            int col = cb * 16 + l15;
            eb[row * CH + col] = acc[cb][r];
        }
}

// ---------------- Phase 2: 48-way partial sum + inverted softmax -----------
// emits att in bf16 (row-major [2048][64]) for direct MFMA A-frag loads
__global__ __launch_bounds__(64) void softmax_kernel(const float* __restrict__ part,
                                                     unsigned short* __restrict__ att_bf) {
    const int row = blockIdx.x;               // b*CH + c, 0..2047
    const int d = threadIdx.x;

    float e = 0.f;
#pragma unroll
    for (int kb = 0; kb < KSPLIT; kb++)
        e += part[(size_t)kb * (BATCH * CH * CH) + (size_t)row * CH + d];

    float m = e;
#pragma unroll
    for (int off = 32; off > 0; off >>= 1) m = fmaxf(m, __shfl_down(m, off));
    m = __shfl(m, 0);

    float en = m - e;

    float mx = en;
#pragma unroll
    for (int off = 32; off > 0; off >>= 1) mx = fmaxf(mx, __shfl_down(mx, off));
    mx = __shfl(mx, 0);

    float ex = __expf(en - mx);
    float s = ex;
#pragma unroll
    for (int off = 32; off > 0; off >>= 1) s += __shfl_down(s, off);
    s = __shfl(s, 0);

    att_bf[(size_t)row * CH + d] = f2bf(ex / s);
}

// ---------------- Phase 3: out = x + g*x*(att @ x), one-shot blocks --------
__global__ __launch_bounds__(256, 4) void proj_kernel(const float* __restrict__ x,
                                                      const unsigned short* __restrict__ att_bf,
                                                      const float* __restrict__ gamma,
                                                      float* __restrict__ out) {
    const int b = blockIdx.x;
    const int n0 = blockIdx.y * NB;
    const int tid = threadIdx.x;
    const int wv = tid >> 6;
    const int lane = tid & 63;
    const int l15 = lane & 15;
    const int quad = lane >> 4;

    __shared__ float xs[CH][XSTR];              // 33.8 KB -> 4 blocks/CU

    const float* xb = x + (size_t)b * CH * NSP;
    float* ob = out + (size_t)b * CH * NSP;

    // A-frags: att bf16 direct global->reg (L2-hot 256KB array, 8 x 16B/lane)
    frag af[2][4];
#pragma unroll
    for (int ks = 0; ks < 2; ks++)
#pragma unroll
        for (int cb = 0; cb < 4; cb++)
            af[ks][cb] = *(const frag*)&att_bf[((size_t)b * CH + cb * 16 + l15) * CH
                                               + ks * 32 + quad * 8];

    // stage x[b][:, n0:n0+NB] fp32 (coalesced float4, rotated columns)
#pragma unroll
    for (int rep = 0; rep < 8; rep++) {
        int idx = rep * 256 + tid;              // 2048 float4 slots, 32/row
        int dd = idx >> 5, nq = idx & 31;
        float4 v = *(const float4*)&xb[(size_t)dd * NSP + n0 + nq * 4];
        *(float4*)&xs[dd][rotn(dd, nq * 4)] = v;
    }
    __syncthreads();                            // the only barrier

    const float g = gamma[0];

    // wave wv owns spatial tiles {2wv, 2wv+1} (16 n each), all 4 channel-blocks
    f32x4 acc[2][4];
#pragma unroll
    for (int t = 0; t < 2; t++)
#pragma unroll
        for (int cb = 0; cb < 4; cb++)
#pragma unroll
            for (int r = 0; r < 4; r++) acc[t][cb][r] = 0.f;

#pragma unroll
    for (int ks = 0; ks < 2; ks++) {            // K=64 -> two K=32 steps
#pragma unroll
        for (int t = 0; t < 2; t++) {
            int n = (wv * 2 + t) * 16 + l15;
            int k0 = ks * 32 + quad * 8;
            // rot index for rows k0..k0+7: ((k0+j)>>3)&3 == quad for all j<8
            int np = (n + (quad << 4)) & (NB - 1);
            uint4 packed;
            packed.x = pack2(xs[k0 + 0][np], xs[k0 + 1][np]);
            packed.y = pack2(xs[k0 + 2][np], xs[k0 + 3][np]);
            packed.z = pack2(xs[k0 + 4][np], xs[k0 + 5][np]);
            packed.w = pack2(xs[k0 + 6][np], xs[k0 + 7][np]);
            frag bf = __builtin_bit_cast(frag, packed);
#pragma unroll
            for (int cb = 0; cb < 4; cb++)
                acc[t][cb] = __builtin_amdgcn_mfma_f32_16x16x32_bf16(af[ks][cb], bf, acc[t][cb], 0, 0, 0);
        }
    }

    // direct stores: 64B segments per quad-row (WRITE_SIZE is pattern-insensitive)
#pragma unroll
    for (int t = 0; t < 2; t++) {
        int n = (wv * 2 + t) * 16 + l15;
#pragma unroll
        for (int cb = 0; cb < 4; cb++)
#pragma unroll
            for (int r = 0; r < 4; r++) {
                int c = cb * 16 + quad * 4 + r;
                float xv = xs[c][rotn(c, n)];
                ob[(size_t)c * NSP + n0 + n] = fmaf(xv * g, acc[t][cb][r], xv);
            }
    }
}

extern "C" void kernel_launch(void* const* d_in, const int* in_sizes, int n_in,
                              void* d_out, int out_size, void* d_ws, size_t ws_size,
                              hipStream_t stream) {
    const float* x = (const float*)d_in[0];
    const float* gamma = (const float*)d_in[1];
    float* out = (float*)d_out;

    float* part = (float*)d_ws;                                   // 48*32*64*64 f32 = 25.2 MB
    unsigned short* att_bf = (unsigned short*)(part + (size_t)KSPLIT * BATCH * CH * CH);  // +256 KB

    gram_kernel<<<dim3(BATCH, KSPLIT), 256, 0, stream>>>(x, part);
    softmax_kernel<<<BATCH * CH, 64, 0, stream>>>(part, att_bf);
    proj_kernel<<<dim3(BATCH, NBLKY), 256, 0, stream>>>(x, att_bf, gamma, out);
}